// Round 1
// baseline (710.436 us; speedup 1.0000x reference)
//
#include <hip/hip_runtime.h>

// Problem: B=16384, S=32, E=128, H=4, DH=32, O=128. fp32 in/out.
// Strategy: split-fp32 (bf16 hi+lo, 3-product MFMA) so scores/softmax are
// fp32-accurate; everything runs on v_mfma_f32_16x16x32_bf16.
// ws layout (unsigned short / bf16 bits), 262144 B total:
//   type t in {0=wq,1=wk,2=wv,3=wo}: base = t*32768
//     hi at base + h*4096 + inner, lo at base + 16384 + h*4096 + inner
//   wq/wk/wv transposed to [h][d][e] (B^T layout), wo to [h][o][dh].
//   scale 1/sqrt(32) folded into wq.

typedef __bf16 bf16x8 __attribute__((ext_vector_type(8)));
typedef float f32x4 __attribute__((ext_vector_type(4)));

union FragU { unsigned int w[4]; bf16x8 v; };

__device__ inline unsigned short f2bf(float f) {
  unsigned int u = __builtin_bit_cast(unsigned int, f);
  u += 0x7FFFu + ((u >> 16) & 1u);   // RTN-even
  return (unsigned short)(u >> 16);
}
__device__ inline float bf2f(unsigned short h) {
  return __builtin_bit_cast(float, (unsigned int)h << 16);
}

__device__ inline bf16x8 ld_frag8(const unsigned short* p) {
  // 8 consecutive bf16, 8-byte aligned -> two ds_read_b64
  FragU f;
  const uint2* q = (const uint2*)p;
  uint2 a = q[0], b = q[1];
  f.w[0] = a.x; f.w[1] = a.y; f.w[2] = b.x; f.w[3] = b.y;
  return f.v;
}

__device__ inline f32x4 mfma16(bf16x8 a, bf16x8 b, f32x4 c) {
  return __builtin_amdgcn_mfma_f32_16x16x32_bf16(a, b, c, 0, 0, 0);
}

__device__ inline void copy16(const unsigned short* src, unsigned short* dst) {
  // 16 bf16: global 16B loads, LDS 8B stores (dst only 8B-aligned)
  uint4 a = *(const uint4*)src;
  uint4 b = *((const uint4*)src + 1);
  uint2* d = (uint2*)dst;
  d[0] = make_uint2(a.x, a.y); d[1] = make_uint2(a.z, a.w);
  d[2] = make_uint2(b.x, b.y); d[3] = make_uint2(b.z, b.w);
}

// ---------------- weight prep: fp32 -> transposed bf16 hi/lo in ws ----------
__global__ void prep_w(const float* __restrict__ wq, const float* __restrict__ wk,
                       const float* __restrict__ wv, const float* __restrict__ wo,
                       unsigned short* __restrict__ wsb) {
  int idx = blockIdx.x * 256 + threadIdx.x;     // 0..65535
  int t = idx >> 14;                            // which weight tensor
  int rem = idx & 16383;
  int hh = rem >> 12;                           // head
  int r2 = rem & 4095;
  const float* src = (t == 0) ? wq : (t == 1) ? wk : (t == 2) ? wv : wo;
  float v = src[rem];
  if (t == 0) v *= 0.17677669529663687f;        // 1/sqrt(32) folded into wq
  int off;
  if (t < 3) { int e = r2 >> 5, d = r2 & 31; off = (hh << 12) + (d << 7) + e; }  // [h][d][e]
  else       { int dh = r2 >> 7, o = r2 & 127; off = (hh << 12) + (o << 5) + dh; } // [h][o][dh]
  unsigned short hi = f2bf(v);
  unsigned short lo = f2bf(v - bf2f(hi));
  wsb[(t << 15) + off] = hi;
  wsb[(t << 15) + 16384 + off] = lo;
}

// ---------------- main fused attention ----------------
// LDS map (unsigned short elements). [36]-padded rows: stride 72B -> <=2-way
// bank aliasing (free, m136), 8B-aligned for ds_read_b64 frags.
#define OFF_WB_HI 0        // weight buffer: proj [32][132] or wo [128][36]
#define OFF_WB_LO 4608
#define OFF_K_HI  9216     // [2][32][36]  (aliased as A after scores)
#define OFF_K_LO  11520
#define OFF_VT_HI 13824    // V^T [2][32 d][36 t]
#define OFF_VT_LO 16128
#define OFF_Q_HI  18432    // [2][2][16][36]  (aliased as Hd after scores)
#define OFF_Q_LO  20736
#define LDS_TOT   23040    // 46080 B -> LDS allows 3 blocks/CU

__global__ __launch_bounds__(256, 2) void attn_fused(
    const float* __restrict__ x, const unsigned short* __restrict__ wsb,
    float* __restrict__ out) {
  __shared__ unsigned short lds[LDS_TOT];
  const int tid = threadIdx.x;
  const int lane = tid & 63;
  const int wid = tid >> 6;       // 4 waves
  const int bl = wid >> 1;        // local batch 0/1
  const int hw = wid & 1;         // 16-row half
  const int sbase = hw << 4;
  const int col = lane & 15;
  const int quad = lane >> 4;

  // ---- stage x -> hi/lo A-fragments in registers (rows sbase..sbase+15) ----
  bf16x8 xh[4], xl[4];
  for (int b = 0; b < 2; ++b) {
    const float4* xg = (const float4*)(x + ((long)(blockIdx.x * 2 + b) << 12));
#pragma unroll
    for (int it = 0; it < 4; ++it) {
      int f4 = it * 256 + tid;            // 1024 float4 per batch
      float4 v = xg[f4];
      int s = f4 >> 5;
      int e = (f4 & 31) << 2;
      unsigned short a0 = f2bf(v.x), b0 = f2bf(v.x - bf2f(a0));
      unsigned short a1 = f2bf(v.y), b1 = f2bf(v.y - bf2f(a1));
      unsigned short a2 = f2bf(v.z), b2 = f2bf(v.z - bf2f(a2));
      unsigned short a3 = f2bf(v.w), b3 = f2bf(v.w - bf2f(a3));
      uint2 ph, pl;
      ph.x = (unsigned)a0 | ((unsigned)a1 << 16);
      ph.y = (unsigned)a2 | ((unsigned)a3 << 16);
      pl.x = (unsigned)b0 | ((unsigned)b1 << 16);
      pl.y = (unsigned)b2 | ((unsigned)b3 << 16);
      *(uint2*)(lds + s * 132 + e) = ph;          // hi tile [32][132] at 0
      *(uint2*)(lds + 4224 + s * 132 + e) = pl;   // lo tile at 4224
    }
    __syncthreads();
    if (bl == b) {
#pragma unroll
      for (int kk = 0; kk < 4; ++kk) {
        xh[kk] = ld_frag8(lds + (sbase + col) * 132 + (kk << 5) + (quad << 3));
        xl[kk] = ld_frag8(lds + 4224 + (sbase + col) * 132 + (kk << 5) + (quad << 3));
      }
    }
    __syncthreads();
  }

  const long batch = (long)blockIdx.x * 2 + bl;
  const f32x4 zero = {0.f, 0.f, 0.f, 0.f};
  f32x4 oacc[8];
#pragma unroll
  for (int i = 0; i < 8; ++i) oacc[i] = zero;

  unsigned short* Kh = lds + OFF_K_HI + bl * 1152;
  unsigned short* Kl = lds + OFF_K_LO + bl * 1152;
  unsigned short* Vh = lds + OFF_VT_HI + bl * 1152;
  unsigned short* Vl = lds + OFF_VT_LO + bl * 1152;
  unsigned short* Qh = lds + OFF_Q_HI + (bl * 2 + hw) * 576;
  unsigned short* Ql = lds + OFF_Q_LO + (bl * 2 + hw) * 576;
  unsigned short* Abuf = lds + OFF_K_HI + bl * 1152;   // alias: A over dead K_hi

  for (int hh = 0; hh < 4; ++hh) {
    __syncthreads();  // prev iter: out-MFMA done with WB, AV done with A region

    // ======== Q = x * WqT (3-product split), M=16,N=32,K=128 ========
    {
      int i0 = tid << 4, d = i0 >> 7, e0 = i0 & 127;
      copy16(wsb + (hh << 12) + i0, lds + OFF_WB_HI + d * 132 + e0);
      copy16(wsb + 16384 + (hh << 12) + i0, lds + OFF_WB_LO + d * 132 + e0);
    }
    __syncthreads();
    f32x4 c0 = zero, c1 = zero;
#pragma unroll
    for (int kk = 0; kk < 4; ++kk) {
      bf16x8 f0 = ld_frag8(lds + OFF_WB_HI + col * 132 + (kk << 5) + (quad << 3));
      bf16x8 f1 = ld_frag8(lds + OFF_WB_HI + (col + 16) * 132 + (kk << 5) + (quad << 3));
      bf16x8 g0 = ld_frag8(lds + OFF_WB_LO + col * 132 + (kk << 5) + (quad << 3));
      bf16x8 g1 = ld_frag8(lds + OFF_WB_LO + (col + 16) * 132 + (kk << 5) + (quad << 3));
      c0 = mfma16(xh[kk], f0, c0); c0 = mfma16(xl[kk], f0, c0); c0 = mfma16(xh[kk], g0, c0);
      c1 = mfma16(xh[kk], f1, c1); c1 = mfma16(xl[kk], f1, c1); c1 = mfma16(xh[kk], g1, c1);
    }
#pragma unroll
    for (int r = 0; r < 4; ++r) {  // C/D: row=quad*4+r, col=lane&15
      int row = (quad << 2) + r;
      unsigned short hi = f2bf(c0[r]), lo = f2bf(c0[r] - bf2f(hi));
      Qh[row * 36 + col] = hi; Ql[row * 36 + col] = lo;
      hi = f2bf(c1[r]); lo = f2bf(c1[r] - bf2f(hi));
      Qh[row * 36 + col + 16] = hi; Ql[row * 36 + col + 16] = lo;
    }
    __syncthreads();

    // ======== K = x * WkT ========
    {
      int i0 = tid << 4, d = i0 >> 7, e0 = i0 & 127;
      copy16(wsb + 32768 + (hh << 12) + i0, lds + OFF_WB_HI + d * 132 + e0);
      copy16(wsb + 32768 + 16384 + (hh << 12) + i0, lds + OFF_WB_LO + d * 132 + e0);
    }
    __syncthreads();
    c0 = zero; c1 = zero;
#pragma unroll
    for (int kk = 0; kk < 4; ++kk) {
      bf16x8 f0 = ld_frag8(lds + OFF_WB_HI + col * 132 + (kk << 5) + (quad << 3));
      bf16x8 f1 = ld_frag8(lds + OFF_WB_HI + (col + 16) * 132 + (kk << 5) + (quad << 3));
      bf16x8 g0 = ld_frag8(lds + OFF_WB_LO + col * 132 + (kk << 5) + (quad << 3));
      bf16x8 g1 = ld_frag8(lds + OFF_WB_LO + (col + 16) * 132 + (kk << 5) + (quad << 3));
      c0 = mfma16(xh[kk], f0, c0); c0 = mfma16(xl[kk], f0, c0); c0 = mfma16(xh[kk], g0, c0);
      c1 = mfma16(xh[kk], f1, c1); c1 = mfma16(xl[kk], f1, c1); c1 = mfma16(xh[kk], g1, c1);
    }
#pragma unroll
    for (int r = 0; r < 4; ++r) {  // K rows are global t = sbase+row
      int row = sbase + (quad << 2) + r;
      unsigned short hi = f2bf(c0[r]), lo = f2bf(c0[r] - bf2f(hi));
      Kh[row * 36 + col] = hi; Kl[row * 36 + col] = lo;
      hi = f2bf(c1[r]); lo = f2bf(c1[r] - bf2f(hi));
      Kh[row * 36 + col + 16] = hi; Kl[row * 36 + col + 16] = lo;
    }
    __syncthreads();

    // ======== V = x * WvT, stored transposed V^T[d][t] ========
    {
      int i0 = tid << 4, d = i0 >> 7, e0 = i0 & 127;
      copy16(wsb + 65536 + (hh << 12) + i0, lds + OFF_WB_HI + d * 132 + e0);
      copy16(wsb + 65536 + 16384 + (hh << 12) + i0, lds + OFF_WB_LO + d * 132 + e0);
    }
    __syncthreads();
    c0 = zero; c1 = zero;
#pragma unroll
    for (int kk = 0; kk < 4; ++kk) {
      bf16x8 f0 = ld_frag8(lds + OFF_WB_HI + col * 132 + (kk << 5) + (quad << 3));
      bf16x8 f1 = ld_frag8(lds + OFF_WB_HI + (col + 16) * 132 + (kk << 5) + (quad << 3));
      bf16x8 g0 = ld_frag8(lds + OFF_WB_LO + col * 132 + (kk << 5) + (quad << 3));
      bf16x8 g1 = ld_frag8(lds + OFF_WB_LO + (col + 16) * 132 + (kk << 5) + (quad << 3));
      c0 = mfma16(xh[kk], f0, c0); c0 = mfma16(xl[kk], f0, c0); c0 = mfma16(xh[kk], g0, c0);
      c1 = mfma16(xh[kk], f1, c1); c1 = mfma16(xl[kk], f1, c1); c1 = mfma16(xh[kk], g1, c1);
    }
#pragma unroll
    for (int r = 0; r < 4; ++r) {  // V[t][d] -> Vt[d][t], t = sbase+row
      int t = sbase + (quad << 2) + r;
      unsigned short hi = f2bf(c0[r]), lo = f2bf(c0[r] - bf2f(hi));
      Vh[col * 36 + t] = hi; Vl[col * 36 + t] = lo;
      hi = f2bf(c1[r]); lo = f2bf(c1[r] - bf2f(hi));
      Vh[(col + 16) * 36 + t] = hi; Vl[(col + 16) * 36 + t] = lo;
    }
    __syncthreads();

    // ======== scores = Q*K^T (M=16,N=32,K=32), fp32-accurate ========
    f32x4 s0 = zero, s1 = zero;
    {
      bf16x8 qhf = ld_frag8(Qh + col * 36 + (quad << 3));
      bf16x8 qlf = ld_frag8(Ql + col * 36 + (quad << 3));
      bf16x8 k0 = ld_frag8(Kh + col * 36 + (quad << 3));
      bf16x8 k1 = ld_frag8(Kh + (col + 16) * 36 + (quad << 3));
      bf16x8 k0l = ld_frag8(Kl + col * 36 + (quad << 3));
      bf16x8 k1l = ld_frag8(Kl + (col + 16) * 36 + (quad << 3));
      s0 = mfma16(qhf, k0, s0); s0 = mfma16(qlf, k0, s0); s0 = mfma16(qhf, k0l, s0);
      s1 = mfma16(qhf, k1, s1); s1 = mfma16(qlf, k1, s1); s1 = mfma16(qhf, k1l, s1);
    }
    // ======== softmax over t, in C-frag registers (quad-wide shfl) ========
    float a0[4], a1[4];
#pragma unroll
    for (int r = 0; r < 4; ++r) {
      float v0 = s0[r], v1 = s1[r];
      float mx = fmaxf(v0, v1);
#pragma unroll
      for (int dx = 1; dx < 16; dx <<= 1) mx = fmaxf(mx, __shfl_xor(mx, dx));
      float e0 = __expf(v0 - mx), e1 = __expf(v1 - mx);
      float sm = e0 + e1;
#pragma unroll
      for (int dx = 1; dx < 16; dx <<= 1) sm += __shfl_xor(sm, dx);
      float inv = 1.0f / sm;
      a0[r] = e0 * inv; a1[r] = e1 * inv;
    }
    __syncthreads();  // all K reads done -> safe to overwrite K_hi with A
#pragma unroll
    for (int r = 0; r < 4; ++r) {
      int row = sbase + (quad << 2) + r;
      Abuf[row * 36 + col] = f2bf(a0[r]);
      Abuf[row * 36 + col + 16] = f2bf(a1[r]);
    }
    __syncthreads();

    // ======== Hd = A * V (M=16,N=32,K=32), V split 2-term ========
    f32x4 hv0 = zero, hv1 = zero;
    {
      bf16x8 af = ld_frag8(Abuf + (sbase + col) * 36 + (quad << 3));
      bf16x8 v0h = ld_frag8(Vh + col * 36 + (quad << 3));
      bf16x8 v1h = ld_frag8(Vh + (col + 16) * 36 + (quad << 3));
      bf16x8 v0l = ld_frag8(Vl + col * 36 + (quad << 3));
      bf16x8 v1l = ld_frag8(Vl + (col + 16) * 36 + (quad << 3));
      hv0 = mfma16(af, v0h, hv0); hv0 = mfma16(af, v0l, hv0);
      hv1 = mfma16(af, v1h, hv1); hv1 = mfma16(af, v1l, hv1);
    }
    // write Hd hi/lo into dead Q region
#pragma unroll
    for (int r = 0; r < 4; ++r) {
      int row = (quad << 2) + r;
      unsigned short hi = f2bf(hv0[r]), lo = f2bf(hv0[r] - bf2f(hi));
      Qh[row * 36 + col] = hi; Ql[row * 36 + col] = lo;
      hi = f2bf(hv1[r]); lo = f2bf(hv1[r] - bf2f(hi));
      Qh[row * 36 + col + 16] = hi; Ql[row * 36 + col + 16] = lo;
    }
    // ======== stage Wo^T [128 o][36] hi/lo ========
    {
      int i0 = tid << 4, o = i0 >> 5, d0 = i0 & 31;
      copy16(wsb + 98304 + (hh << 12) + i0, lds + OFF_WB_HI + o * 36 + d0);
      copy16(wsb + 98304 + 16384 + (hh << 12) + i0, lds + OFF_WB_LO + o * 36 + d0);
    }
    __syncthreads();
    // ======== out += Hd * Wo (M=16,N=128,K=32), 3-product split ========
    {
      bf16x8 dh = ld_frag8(Qh + col * 36 + (quad << 3));
      bf16x8 dl = ld_frag8(Ql + col * 36 + (quad << 3));
#pragma unroll
      for (int t8 = 0; t8 < 8; ++t8) {
        bf16x8 wh = ld_frag8(lds + OFF_WB_HI + ((t8 << 4) + col) * 36 + (quad << 3));
        bf16x8 wl = ld_frag8(lds + OFF_WB_LO + ((t8 << 4) + col) * 36 + (quad << 3));
        oacc[t8] = mfma16(dh, wh, oacc[t8]);
        oacc[t8] = mfma16(dl, wh, oacc[t8]);
        oacc[t8] = mfma16(dh, wl, oacc[t8]);
      }
    }
  }  // head loop

  // ---- store out [16 rows][128 cols] fp32 ----
  float* og = out + batch * 4096;
#pragma unroll
  for (int t8 = 0; t8 < 8; ++t8) {
#pragma unroll
    for (int r = 0; r < 4; ++r) {
      og[(sbase + (quad << 2) + r) * 128 + (t8 << 4) + col] = oacc[t8][r];
    }
  }
}

extern "C" void kernel_launch(void* const* d_in, const int* in_sizes, int n_in,
                              void* d_out, int out_size, void* d_ws, size_t ws_size,
                              hipStream_t stream) {
  const float* x = (const float*)d_in[0];
  const float* wq = (const float*)d_in[1];
  const float* wk = (const float*)d_in[2];
  const float* wv = (const float*)d_in[3];
  const float* wo = (const float*)d_in[4];
  float* out = (float*)d_out;
  unsigned short* wsb = (unsigned short*)d_ws;  // needs 262144 B
  hipLaunchKernelGGL(prep_w, dim3(256), dim3(256), 0, stream, wq, wk, wv, wo, wsb);
  hipLaunchKernelGGL(attn_fused, dim3(8192), dim3(256), 0, stream, x, wsb, out);
}